// Round 2
// baseline (1643.795 us; speedup 1.0000x reference)
//
#include <hip/hip_runtime.h>
#include <hip/hip_bf16.h>

// MultiAttention: S=1024, B=8, D=1024, H=8
// Per-head pipeline (bf16 MFMA GEMMs, fp32 accumulate), peak ws = 121 MB:
//  once: Xb=bf16(x); bsum=sum_h b_out; out[sb][f]=bsum[f]
//  per head h:
//    Wbh=bf16(w_in[h]); Woh=bf16(w_out[h])
//    Q/K/V[sb][e] = Xb @ W^T + b                (8192x1024x1024 each)
//    SC[b][s][t] = (Q_b K_b^T)/32  fp32         (8x 1024^3)
//    P = softmax rows (bf16)
//    VT[b][e][t] = V transpose                  (VT aliases Q)
//    O[sb][e] = P_b VT_b^T                      (O aliases K)
//    out += O @ Woh^T                           (fp32 accumulate)

typedef __attribute__((ext_vector_type(8))) __bf16 bf16x8;
typedef __attribute__((ext_vector_type(4))) float f32x4;

__device__ __forceinline__ unsigned short f2bf(float f) {
  union { float f; unsigned u; } x; x.f = f;
  unsigned r = x.u + 0x7fffu + ((x.u >> 16) & 1u);   // RNE
  return (unsigned short)(r >> 16);
}

__device__ __forceinline__ void gload16(const void* g, void* l) {
  __builtin_amdgcn_global_load_lds(
      (const __attribute__((address_space(1))) void*)g,
      (__attribute__((address_space(3))) void*)l, 16, 0, 0);
}

// ---------------- generic NT GEMM: C = alpha*(A @ B^T) [+ bias] ---------------
// A: [M][K] bf16 (row stride lda), B: [N][K] bf16 (row stride ldb)
// batched over blockIdx.z with per-batch element offsets.
// Tile 128x128, BK=32, 256 threads (4 waves, 2x2), mfma 16x16x32 bf16.
// CMODE: 0 = fp32 store, 1 = bf16 store, 2 = fp32 accumulate (C += ...)
template<int CMODE, int HAS_BIAS>
__global__ __launch_bounds__(256, 2)
void gemm_nt(const unsigned short* __restrict__ A,
             const unsigned short* __restrict__ B,
             void* __restrict__ C,
             const float* __restrict__ bias,
             float alpha, int K,
             long lda, long ldb, long ldc,
             long offA_b, long offB_b, long offC_b)
{
  __shared__ __align__(16) unsigned short As[128 * 32];
  __shared__ __align__(16) unsigned short Bs[128 * 32];

  const int z = blockIdx.z;
  const unsigned short* Ab = A + z * offA_b + (long)blockIdx.x * 128 * lda;
  const unsigned short* Bb = B + z * offB_b + (long)blockIdx.y * 128 * ldb;

  const int tid  = threadIdx.x;
  const int lane = tid & 63;
  const int w    = tid >> 6;
  const int wr   = w >> 1, wc = w & 1;

  // staging: chunk c covers LDS elements [c*8, c*8+8) == row (c>>2), k ((c&3)*8)
  const int c0 = tid, c1 = tid + 256;
  const int r0 = c0 >> 2, q0 = (c0 & 3) * 8;
  const int r1 = c1 >> 2, q1 = (c1 & 3) * 8;
  const unsigned short* gA0 = Ab + (long)r0 * lda + q0;
  const unsigned short* gA1 = Ab + (long)r1 * lda + q1;
  const unsigned short* gB0 = Bb + (long)r0 * ldb + q0;
  const unsigned short* gB1 = Bb + (long)r1 * ldb + q1;

  f32x4 acc[4][4] = {};

  const int arow = wr * 64 + (lane & 15);
  const int brow = wc * 64 + (lane & 15);
  const int kof  = (lane >> 4) * 8;

  for (int kt = 0; kt < K; kt += 32) {
    gload16(gA0, As + c0 * 8);
    gload16(gA1, As + c1 * 8);
    gload16(gB0, Bs + c0 * 8);
    gload16(gB1, Bs + c1 * 8);
    gA0 += 32; gA1 += 32; gB0 += 32; gB1 += 32;
    __syncthreads();

    bf16x8 af[4], bg[4];
#pragma unroll
    for (int m = 0; m < 4; ++m)
      af[m] = *(const bf16x8*)(As + (arow + m * 16) * 32 + kof);
#pragma unroll
    for (int n = 0; n < 4; ++n)
      bg[n] = *(const bf16x8*)(Bs + (brow + n * 16) * 32 + kof);

#pragma unroll
    for (int m = 0; m < 4; ++m)
#pragma unroll
      for (int n = 0; n < 4; ++n)
        acc[m][n] = __builtin_amdgcn_mfma_f32_16x16x32_bf16(af[m], bg[n], acc[m][n], 0, 0, 0);
    __syncthreads();
  }

  // epilogue: C/D layout (m89-verified): col = lane&15, row = (lane>>4)*4 + j
  const long crow0 = (long)blockIdx.x * 128 + wr * 64;
  const long ccol0 = (long)blockIdx.y * 128 + wc * 64;
  const long cbase = z * offC_b;

#pragma unroll
  for (int m = 0; m < 4; ++m) {
#pragma unroll
    for (int n = 0; n < 4; ++n) {
      const long col = ccol0 + n * 16 + (lane & 15);
      const float badd = HAS_BIAS ? bias[col] : 0.0f;
#pragma unroll
      for (int j = 0; j < 4; ++j) {
        const long row = crow0 + m * 16 + (lane >> 4) * 4 + j;
        const float v = acc[m][n][j] * alpha + badd;
        const long idx = cbase + row * ldc + col;
        if (CMODE == 1)      ((unsigned short*)C)[idx] = f2bf(v);
        else if (CMODE == 2) ((float*)C)[idx] += v;
        else                 ((float*)C)[idx] = v;
      }
    }
  }
}

// ---------------- softmax over rows of 1024 (fp32 in, bf16 out) ---------------
__global__ __launch_bounds__(256)
void softmax_k(const float* __restrict__ SC, unsigned short* __restrict__ P)
{
  const long row = blockIdx.x;
  const float* s = SC + (row << 10);
  unsigned short* p = P + (row << 10);
  const int tid = threadIdx.x;

  float4 v = ((const float4*)s)[tid];
  float mx = fmaxf(fmaxf(v.x, v.y), fmaxf(v.z, v.w));
#pragma unroll
  for (int o = 32; o >= 1; o >>= 1) mx = fmaxf(mx, __shfl_xor(mx, o));
  __shared__ float red[8];
  const int w = tid >> 6, lane = tid & 63;
  if (lane == 0) red[w] = mx;
  __syncthreads();
  mx = fmaxf(fmaxf(red[0], red[1]), fmaxf(red[2], red[3]));

  float e0 = __expf(v.x - mx), e1 = __expf(v.y - mx);
  float e2 = __expf(v.z - mx), e3 = __expf(v.w - mx);
  float sum = e0 + e1 + e2 + e3;
#pragma unroll
  for (int o = 32; o >= 1; o >>= 1) sum += __shfl_xor(sum, o);
  if (lane == 0) red[4 + w] = sum;
  __syncthreads();
  sum = red[4] + red[5] + red[6] + red[7];
  const float inv = 1.0f / sum;

  ushort4 o4;
  o4.x = f2bf(e0 * inv); o4.y = f2bf(e1 * inv);
  o4.z = f2bf(e2 * inv); o4.w = f2bf(e3 * inv);
  ((ushort4*)p)[tid] = o4;
}

// ---------- V transpose per b: VT[b][e][t] = V[(t*8+b)*1024 + e] --------------
__global__ __launch_bounds__(256)
void transpose_v(const unsigned short* __restrict__ V, unsigned short* __restrict__ VT)
{
  const int b = blockIdx.z;
  __shared__ unsigned short tile[32][33];
  const int t0 = blockIdx.x * 32, e0 = blockIdx.y * 32;
  const int tx = threadIdx.x & 31, ty = threadIdx.x >> 5;
#pragma unroll
  for (int i = 0; i < 4; ++i) {
    const int tr = ty + i * 8;
    tile[tr][tx] = V[(long)(t0 + tr) * 8192 + b * 1024 + e0 + tx];
  }
  __syncthreads();
#pragma unroll
  for (int i = 0; i < 4; ++i) {
    const int er = ty + i * 8;
    VT[(long)b * 1048576 + (long)(e0 + er) * 1024 + t0 + tx] = tile[tx][er];
  }
}

// ---------------- converters / init -------------------------------------------
__global__ __launch_bounds__(256)
void conv_bf16(const float* __restrict__ in, unsigned short* __restrict__ out, long n4)
{
  const long i = (long)blockIdx.x * 256 + threadIdx.x;
  if (i >= n4) return;
  const float4 v = ((const float4*)in)[i];
  ushort4 o; o.x = f2bf(v.x); o.y = f2bf(v.y); o.z = f2bf(v.z); o.w = f2bf(v.w);
  ((ushort4*)out)[i] = o;
}

__global__ __launch_bounds__(256)
void bias_sum_k(const float* __restrict__ b_out, float* __restrict__ bsum)
{
  const int f = blockIdx.x * 256 + threadIdx.x;
  if (f < 1024) {
    float s = 0.f;
#pragma unroll
    for (int h = 0; h < 8; ++h) s += b_out[h * 1024 + f];
    bsum[f] = s;
  }
}

// out[sb][f] = bsum[f]  (8M floats, float4)
__global__ __launch_bounds__(256)
void out_init_k(float* __restrict__ out, const float* __restrict__ bsum)
{
  const long i = (long)blockIdx.x * 256 + threadIdx.x;   // over 2M float4
  ((float4*)out)[i] = ((const float4*)bsum)[i & 255];
}

// ---------------- launch ------------------------------------------------------
extern "C" void kernel_launch(void* const* d_in, const int* in_sizes, int n_in,
                              void* d_out, int out_size, void* d_ws, size_t ws_size,
                              hipStream_t stream)
{
  const float* x     = (const float*)d_in[0];
  const float* w_in  = (const float*)d_in[1];
  const float* b_in  = (const float*)d_in[2];
  const float* w_out = (const float*)d_in[3];
  const float* b_out = (const float*)d_in[4];
  float* out = (float*)d_out;

  char* ws = (char*)d_ws;
  const long MB = 1ll << 20;
  unsigned short* Xb   = (unsigned short*)(ws);              // 16 MB
  float*          bsum = (float*)         (ws + 16 * MB);    // 4 KB
  unsigned short* Wbh  = (unsigned short*)(ws + 17 * MB);    // 6 MB
  unsigned short* Woh  = (unsigned short*)(ws + 23 * MB);    // 2 MB
  unsigned short* Qh   = (unsigned short*)(ws + 25 * MB);    // 16 MB
  unsigned short* Kh   = (unsigned short*)(ws + 41 * MB);    // 16 MB
  unsigned short* Vh   = (unsigned short*)(ws + 57 * MB);    // 16 MB
  float*          SC   = (float*)         (ws + 73 * MB);    // 32 MB (fp32)
  unsigned short* P    = (unsigned short*)(ws + 105 * MB);   // 16 MB
  unsigned short* VT = Qh;   // Q dead after scores
  unsigned short* O  = Kh;   // K dead after scores
  // peak ws use: 121 MB

  dim3 blk(256);

  conv_bf16 <<<8192, blk, 0, stream>>>(x, Xb, 2097152);
  bias_sum_k<<<4,    blk, 0, stream>>>(b_out, bsum);
  out_init_k<<<8192, blk, 0, stream>>>(out, bsum);

  for (int h = 0; h < 8; ++h) {
    conv_bf16<<<3072, blk, 0, stream>>>(w_in  + (long)h * 3145728, Wbh, 786432);
    conv_bf16<<<1024, blk, 0, stream>>>(w_out + (long)h * 1048576, Woh, 262144);

    dim3 g1(64, 8, 1);
    gemm_nt<1,1><<<g1, blk, 0, stream>>>(Xb, Wbh,           Qh, b_in + h * 3072,        1.0f, 1024,
        1024, 1024, 1024,  0, 0, 0);
    gemm_nt<1,1><<<g1, blk, 0, stream>>>(Xb, Wbh + 1048576, Kh, b_in + h * 3072 + 1024, 1.0f, 1024,
        1024, 1024, 1024,  0, 0, 0);
    gemm_nt<1,1><<<g1, blk, 0, stream>>>(Xb, Wbh + 2097152, Vh, b_in + h * 3072 + 2048, 1.0f, 1024,
        1024, 1024, 1024,  0, 0, 0);

    // scores: per b: SC[b] = (Q_b K_b^T)/32, fp32.  Q_b rows: (s*8+b)*1024
    dim3 g2(8, 8, 8);
    gemm_nt<0,0><<<g2, blk, 0, stream>>>(Qh, Kh, SC, nullptr, 0.03125f, 1024,
        8192, 8192, 1024,  1024, 1024, 1048576);

    softmax_k  <<<8192, blk, 0, stream>>>(SC, P);
    transpose_v<<<dim3(32, 32, 8), blk, 0, stream>>>(Vh, VT);

    // PV: O[(s*8+b)*1024 + e] = sum_t P[b][s][t] VT[b][e][t]
    gemm_nt<1,0><<<g2, blk, 0, stream>>>(P, VT, O, nullptr, 1.0f, 1024,
        1024, 1024, 8192,  1048576, 1048576, 1024);

    // out += O @ Woh^T
    gemm_nt<2,0><<<g1, blk, 0, stream>>>(O, Woh, out, nullptr, 1.0f, 1024,
        1024, 1024, 1024,  0, 0, 0);
  }
}